// Round 20
// baseline (143.349 us; speedup 1.0000x reference)
//
#include <hip/hip_runtime.h>
#include <hip/hip_fp16.h>
#include <stdint.h>

#define N_NODES 100000
#define N_EDGES 1600000
#define N_FEAT 256
#define HIDDEN 128

// ---- bucketed CSR build ----
#define BKT_SH 8
#define BKT_RANGE 256                                   // nodes per bucket
#define NBKT ((N_NODES + BKT_RANGE - 1) >> BKT_SH)      // 391
#define BKT_CAP 4608                                    // mean 4096 + 8 sigma
#define BIN_CHUNK 4096
#define NWG_BIN ((N_EDGES + BIN_CHUNK - 1) / BIN_CHUNK) // 391

typedef __attribute__((ext_vector_type(8))) _Float16 f16x8;
typedef __attribute__((ext_vector_type(4))) float f32x4;

// ---------------- W -> fp16 + zero bucket cursors (merged) ----------

__global__ __launch_bounds__(256) void k_wconv_zero(const float* __restrict__ W,
                                                    short* __restrict__ w16,
                                                    int* __restrict__ gcur) {
    int i = blockIdx.x * 256 + threadIdx.x;
    if (i < HIDDEN * N_FEAT) {
        __half h = __float2half_rn(W[i]);
        w16[i] = *(short*)&h;
    }
    if (i < NBKT) gcur[i] = 0;
}

// ---------------- bin edges into target-range buckets ----------------

__global__ __launch_bounds__(256) void k_bin(const int* __restrict__ row,
                                             const int* __restrict__ col,
                                             int* __restrict__ gcur,
                                             int2* __restrict__ recs) {
    __shared__ int hcnt[NBKT];
    __shared__ int hbase[NBKT];
    const int t = threadIdx.x;
    for (int i = t; i < NBKT; i += 256) hcnt[i] = 0;
    __syncthreads();
    const int e0 = blockIdx.x * BIN_CHUNK;
    int cs[16], ss[16];
#pragma unroll
    for (int i = 0; i < 16; ++i) {
        int e = e0 + t + i * 256;
        if (e < N_EDGES) {
            cs[i] = col[e];
            ss[i] = row[e];
            atomicAdd(&hcnt[cs[i] >> BKT_SH], 1);
        } else {
            cs[i] = -1;
        }
    }
    __syncthreads();
    for (int i = t; i < NBKT; i += 256) {
        int c = hcnt[i];
        hbase[i] = (c > 0) ? atomicAdd(&gcur[i], c) : 0;
    }
    __syncthreads();
    for (int i = t; i < NBKT; i += 256) hcnt[i] = 0;  // reuse as local cursor
    __syncthreads();
#pragma unroll
    for (int i = 0; i < 16; ++i) {
        if (cs[i] >= 0) {
            int bkt = cs[i] >> BKT_SH;
            int pos = hbase[bkt] + atomicAdd(&hcnt[bkt], 1);
            if (pos < BKT_CAP)
                recs[(size_t)bkt * BKT_CAP + pos] = make_int2(cs[i], ss[i]);
        }
    }
}

// ---------------- per-bucket: histogram + scan + srow/dinv + scatter -------
// Round 20: merges k_hist and k_slot2. The per-bucket prefix scan lives in
// LDS, so the scatter can run in the same kernel (recs second pass is
// L2-hot, 32KB/bucket) -- saves one launch and a 12.8 MB recs re-read.

__global__ __launch_bounds__(256) void k_histslot(const int* __restrict__ gcur,
                                                  const int2* __restrict__ recs,
                                                  int2* __restrict__ srow,
                                                  float* __restrict__ dinv,
                                                  int* __restrict__ edge_src) {
    __shared__ int hc[BKT_RANGE];
    __shared__ int ts[BKT_RANGE];
    const int b = blockIdx.x, t = threadIdx.x;
    hc[t] = 0;
    __syncthreads();
    int n = gcur[b];
    if (n > BKT_CAP) n = BKT_CAP;
    const int2* rb = recs + (size_t)b * BKT_CAP;
    for (int i = t; i < n; i += 256)
        atomicAdd(&hc[rb[i].x & (BKT_RANGE - 1)], 1);
    __syncthreads();
    int cnt = hc[t];
    // inclusive Hillis-Steele scan in LDS
    int val = cnt;
    ts[t] = val;
    __syncthreads();
    for (int off = 1; off < 256; off <<= 1) {
        int other = (t >= off) ? ts[t - off] : 0;
        __syncthreads();
        val += other;
        ts[t] = val;
        __syncthreads();
    }
    int start = b * BKT_CAP + (val - cnt);  // exclusive prefix + slab base
    int node = (b << BKT_SH) + t;
    if (node < N_NODES) {
        srow[node] = make_int2(start, start + cnt);
        dinv[node] = rsqrtf((float)(cnt + 1));  // +1 self-loop
    }
    __syncthreads();
    // reuse LDS: hc = per-node cursor, ts = per-node slab start
    hc[t] = 0;
    ts[t] = start;
    __syncthreads();
    for (int i = t; i < n; i += 256) {
        int2 r = rb[i];
        int l = r.x & (BKT_RANGE - 1);
        int pos = ts[l] + atomicAdd(&hc[l], 1);
        edge_src[pos] = r.y;
    }
}

// ---------------- h2 = fp16(x @ W.T * dinv) via fp16 MFMA ----------------
// Round 20: KS 32 -> 64. The synchronous loop is barrier-latency-bound;
// halving iterations (8 -> 4) halves barrier pairs while keeping the exact
// stage->sync->compute->sync shape that compiles cleanly (ILP prefetch and
// no-LDS variants both failed: spill / load serialization). LDS 27648 B
// still allows 5 blocks/CU. Spill tell = WRITE > 25.6 MB.
#define TM 64
#define KS 64
#define LDR 72   // 64 halves + 8 pad -> 144 B rows, 16B-aligned slots

__global__ __launch_bounds__(256) void k_gemm(const float* __restrict__ x,
                                              const short* __restrict__ w16,
                                              const float* __restrict__ dinv,
                                              __half* __restrict__ h2) {
    __shared__ short xh[TM * LDR];      // 9216 B (fp16)
    __shared__ short wh[HIDDEN * LDR];  // 18432 B (fp16)
    const int t = threadIdx.x;
    const int lane = t & 63;
    const int wv = t >> 6;
    const int wr = wv >> 1, wc = wv & 1;   // 2x2 wave grid; wave tile 32x64
    const int row0 = blockIdx.x * TM;

    f32x4 acc[2][4];
#pragma unroll
    for (int m = 0; m < 2; ++m)
#pragma unroll
        for (int n = 0; n < 4; ++n) acc[m][n] = (f32x4)0.f;

    // x staging: thread -> row rx (0..63), 16-float slot sx (0..3)
    const int rx = t >> 2, sx = t & 3;
    const int gxr = row0 + rx;
    const bool xok = (gxr < N_NODES);
    // W staging: thread covers rows rw0, rw1 at 16-half slot slw
    const int rw0 = t >> 2, rw1 = (t >> 2) + 64, slw = (t & 3) * 16;

    for (int k0 = 0; k0 < N_FEAT; k0 += KS) {
        // ---- stage x: fp32 -> fp16 in registers -> LDS (16 floats/thr) ----
        float4 f[4];
#pragma unroll
        for (int q = 0; q < 4; ++q) {
            f[q] = make_float4(0.f, 0.f, 0.f, 0.f);
            if (xok) f[q] = *(const float4*)&x[(size_t)gxr * N_FEAT + k0 + sx * 16 + q * 4];
        }
        {
            __half2 p0 = __floats2half2_rn(f[0].x, f[0].y);
            __half2 p1 = __floats2half2_rn(f[0].z, f[0].w);
            __half2 p2 = __floats2half2_rn(f[1].x, f[1].y);
            __half2 p3 = __floats2half2_rn(f[1].z, f[1].w);
            __half2 p4 = __floats2half2_rn(f[2].x, f[2].y);
            __half2 p5 = __floats2half2_rn(f[2].z, f[2].w);
            __half2 p6 = __floats2half2_rn(f[3].x, f[3].y);
            __half2 p7 = __floats2half2_rn(f[3].z, f[3].w);
            int4 pk0 = make_int4(*(int*)&p0, *(int*)&p1, *(int*)&p2, *(int*)&p3);
            int4 pk1 = make_int4(*(int*)&p4, *(int*)&p5, *(int*)&p6, *(int*)&p7);
            int o = rx * LDR + sx * 16;
            *(int4*)&xh[o] = pk0;
            *(int4*)&xh[o + 8] = pk1;
        }
        // ---- stage W: fp16 direct copy (global -> reg -> LDS) ----
        {
            int4 a0 = *(const int4*)&w16[(size_t)rw0 * N_FEAT + k0 + slw];
            int4 a1 = *(const int4*)&w16[(size_t)rw0 * N_FEAT + k0 + slw + 8];
            int4 a2 = *(const int4*)&w16[(size_t)rw1 * N_FEAT + k0 + slw];
            int4 a3 = *(const int4*)&w16[(size_t)rw1 * N_FEAT + k0 + slw + 8];
            *(int4*)&wh[rw0 * LDR + slw] = a0;
            *(int4*)&wh[rw0 * LDR + slw + 8] = a1;
            *(int4*)&wh[rw1 * LDR + slw] = a2;
            *(int4*)&wh[rw1 * LDR + slw + 8] = a3;
        }
        __syncthreads();
        // ---- fragments + MFMA: two K=32 sub-steps per staged tile ----
        const int fr = lane & 15, fs = lane >> 4;
#pragma unroll
        for (int ks = 0; ks < 2; ++ks) {
            f16x8 ah[2], bh[4];
#pragma unroll
            for (int m = 0; m < 2; ++m) {
                int o = (wr * 32 + m * 16 + fr) * LDR + ks * 32 + fs * 8;
                ah[m] = *(const f16x8*)&xh[o];
            }
#pragma unroll
            for (int n = 0; n < 4; ++n) {
                int o = (wc * 64 + n * 16 + fr) * LDR + ks * 32 + fs * 8;
                bh[n] = *(const f16x8*)&wh[o];
            }
#pragma unroll
            for (int m = 0; m < 2; ++m)
#pragma unroll
                for (int n = 0; n < 4; ++n)
                    acc[m][n] = __builtin_amdgcn_mfma_f32_16x16x32_f16(ah[m], bh[n], acc[m][n], 0, 0, 0);
        }
        __syncthreads();
    }
    // ---- epilogue: h2 = fp16(acc * dinv) only ----
    // C/D layout: col = lane&15, row = (lane>>4)*4 + r
    const int cr = (lane >> 4) * 4, cc = lane & 15;
#pragma unroll
    for (int m = 0; m < 2; ++m) {
        int gr0 = row0 + wr * 32 + m * 16 + cr;
#pragma unroll
        for (int r = 0; r < 4; ++r) {
            int gr = gr0 + r;
            if (gr < N_NODES) {
                float d = dinv[gr];
#pragma unroll
                for (int n = 0; n < 4; ++n) {
                    int gc = wc * 64 + n * 16 + cc;
                    h2[(size_t)gr * HIDDEN + gc] = __float2half_rn(acc[m][n][r] * d);
                }
            }
        }
    }
}

// ---------------- gather-accumulate per node ----------------
// FROZEN (rounds 12/17 form, incl. ADDRESSING): idx[]/wt[] arrays, ternary
// clamp, separate v[] load loop with hp[(unsigned)idx*64u+lane], fmac-with-wt
// accumulate. This exact token form gives VGPR 36 / occupancy 58% / 68.5us.
// Byte-offset variant (char* + min clamp) => VGPR 48 / 42% / 76us (round 18).

__global__ __launch_bounds__(256) void k_gather(const int2* __restrict__ srow,
                                                const int* __restrict__ edge_src,
                                                const float* __restrict__ dinv,
                                                const __half* __restrict__ h2s,
                                                const float* __restrict__ b,
                                                const float* __restrict__ pa,
                                                float* __restrict__ out) {
    int n = (blockIdx.x * 256 + threadIdx.x) >> 6;
    int lane = threadIdx.x & 63;
    if (n >= N_NODES) return;
    int2 se = srow[n];
    int start = se.x, end = se.y;
    float dn = dinv[n];
    const __half2* hp = (const __half2*)h2s;  // [N_NODES][64] half2
    // self term (sequential read of own row; h2 is pre-scaled by dinv[src])
    float2 base = __half22float2(hp[(unsigned)n * 64u + lane]);
    float2 acc = make_float2(0.f, 0.f);
    for (int e = start; e < end; e += 16) {
        int idx[16];
        float wt[16];
#pragma unroll
        for (int i = 0; i < 16; ++i) {
            int ee = e + i;
            int cl = (ee < end) ? ee : (end - 1);
            idx[i] = edge_src[cl];
            wt[i] = (ee < end) ? 1.f : 0.f;
        }
        __half2 v[16];
#pragma unroll
        for (int i = 0; i < 16; ++i) v[i] = hp[(unsigned)idx[i] * 64u + lane];
#pragma unroll
        for (int i = 0; i < 16; ++i) {
            float2 f = __half22float2(v[i]);
            acc.x += f.x * wt[i];
            acc.y += f.y * wt[i];
        }
    }
    float2 bb = *(const float2*)&b[lane * 2];
    float2 aa = *(const float2*)&pa[lane * 2];
    float2 r;
    r.x = dn * (base.x + acc.x) + bb.x;
    r.y = dn * (base.y + acc.y) + bb.y;
    r.x = r.x > 0.f ? r.x : r.x * aa.x;
    r.y = r.y > 0.f ? r.y : r.y * aa.y;
    *(float2*)&out[(size_t)n * HIDDEN + lane * 2] = r;
}

// ---------------- launch ----------------

extern "C" void kernel_launch(void* const* d_in, const int* in_sizes, int n_in,
                              void* d_out, int out_size, void* d_ws, size_t ws_size,
                              hipStream_t stream) {
    const float* x  = (const float*)d_in[0];
    const int*   ei = (const int*)d_in[1];   // [2, E] int32
    const float* W  = (const float*)d_in[2];
    const float* b  = (const float*)d_in[3];
    const float* pa = (const float*)d_in[4];
    float* out = (float*)d_out;

    const int* row = ei;            // sources
    const int* col = ei + N_EDGES;  // targets

    // ---- workspace layout (≈49 MB) ----
    char* w = (char*)d_ws;
    __half* h2      = (__half*)w;                                  // 25.6 MB
    int2*  srow     = (int2*)(w + (size_t)(N_NODES + 1) * HIDDEN * 2); // 800 KB
    int*   edge_src = (int*)(srow + N_NODES);                      // slab CSR: NBKT*BKT_CAP*4 = 7.2 MB
    float* dinv     = (float*)(edge_src + (size_t)NBKT * BKT_CAP); // 400 KB
    short* w16      = (short*)(dinv + N_NODES);                    // 64 KB
    int*   gcur     = (int*)(w16 + HIDDEN * N_FEAT);               // 1.6 KB
    int2*  recs     = (int2*)(((uintptr_t)(gcur + NBKT) + 15) & ~(uintptr_t)15);  // 14.4 MB

    k_wconv_zero<<<(HIDDEN * N_FEAT + 255) / 256, 256, 0, stream>>>(W, w16, gcur);
    k_bin<<<NWG_BIN, 256, 0, stream>>>(row, col, gcur, recs);
    k_histslot<<<NBKT, 256, 0, stream>>>(gcur, recs, srow, dinv, edge_src);
    k_gemm<<<(N_NODES + TM - 1) / TM, 256, 0, stream>>>(x, w16, dinv, h2);
    k_gather<<<(int)(((size_t)N_NODES * 64 + 255) / 256), 256, 0, stream>>>(
        srow, edge_src, dinv, h2, b, pa, out);
}